// Round 13
// baseline (157.962 us; speedup 1.0000x reference)
//
#include <hip/hip_runtime.h>
#include <hip/hip_cooperative_groups.h>

namespace cg = cooperative_groups;

// ---------------------------------------------------------------------------
// Devault_Single_CCNN: only the LAST timestep feeds the head -> compute only
// the causal receptive field. Every layer is a stride-2 kernel-5 conv in
// index space: Out[q] = sum_k W[k] In[2q+k], lengths 509->253->125->61->29->
// 13->5->1. bf16 MFMA 16x16x32, fp32 accumulate.
// ONE cooperative dispatch (r12 lesson: 4 different multi-dispatch configs
// all land ~66us while kernel models sum to ~40 -> the gap is inter-dispatch
// serialization; remove it). 256 blocks (4qt x 64b) x 512 thr, 1 block/CU,
// grid.sync() between phases:
//   W : weight-norm + MFMA-B pre-swizzle (2048 waves cover 896 channels)
//   P0: gather emb -> LDS (133 rows, full 640B) -> L0 -> A0 global (64 rows)
//   P1: stage A0 (73 rows) -> L1 (LDS) -> L2 -> L2out global
//   P2: qt==0 blocks only: L3..L6 + FC head -> out
// All phases keep the r12-proven no-spill geometry: 512 thr, bounded per-tap
// B preloads (<=10 frags), static-indexed register arrays.
// Masking invariant: MFMA C-row m depends only on A-row m; garbage rows are
// finite and feed only outputs never read by the valid chain (audited per
// phase below). All LDS overreads stay inside the 87.8KB arena.
// ---------------------------------------------------------------------------

typedef __attribute__((ext_vector_type(8))) short bfrag8;   // 8 bf16
typedef __attribute__((ext_vector_type(4))) float floatx4;  // MFMA acc
typedef __attribute__((ext_vector_type(4))) short short4v;
typedef __attribute__((ext_vector_type(4))) float float4v;

__device__ __forceinline__ unsigned short f2bf(float f) {
  union { float f; unsigned u; } v; v.f = f;
  unsigned r = v.u + 0x7fffu + ((v.u >> 16) & 1u);  // RNE
  return (unsigned short)(r >> 16);
}
__device__ __forceinline__ float bf2f(unsigned short h) {
  union { unsigned u; float f; } v; v.u = ((unsigned)h) << 16;
  return v.f;
}
__device__ __forceinline__ int swz(int row) { return ((row >> 1) & 7) << 4; }

// ---------------------------------------------------------------------------
// conv_l (proven r12): K=640 layer, NMTW m-tiles at mt0 x NOTW ot's at
// og*NOTW. B per-tap preload (<=8 frags = 32 VGPR). A from swizzled
// 256B-pitch LDS. Stores masked to qq < MCAP (inside destination alloc).
// ---------------------------------------------------------------------------
template<int NMTW, int NOTW, int MCAP>
__device__ __forceinline__ void conv_l(const char* bi, char* bo,
    const unsigned short* __restrict__ WBl, const float* __restrict__ bias,
    int mt0, int og, int qb, int kg, int lane) {
  floatx4 acc[NMTW][NOTW];
#pragma unroll
  for (int m = 0; m < NMTW; ++m)
#pragma unroll
    for (int j = 0; j < NOTW; ++j) acc[m][j] = floatx4{0.f, 0.f, 0.f, 0.f};
#pragma unroll
  for (int tap = 0; tap < 5; ++tap) {
    bfrag8 bfs[NOTW][4];
#pragma unroll
    for (int j = 0; j < NOTW; ++j)
#pragma unroll
      for (int cs = 0; cs < 4; ++cs)
        bfs[j][cs] = *(const bfrag8*)(WBl +
            (size_t)((((og * NOTW + j) * 20 + (tap << 2) + cs) << 6) + lane) * 8);
#pragma unroll
    for (int cs = 0; cs < 4; ++cs) {
      const int cb = (cs << 6) + (kg << 4);
#pragma unroll
      for (int m = 0; m < NMTW; ++m) {
        const int row = (((mt0 + m) << 4) + qb) * 2 + tap;
        const bfrag8 a = *(const bfrag8*)(bi + (((row << 8) + cb) ^ swz(row)));
#pragma unroll
        for (int j = 0; j < NOTW; ++j)
          acc[m][j] = __builtin_amdgcn_mfma_f32_16x16x32_bf16(a, bfs[j][cs], acc[m][j], 0, 0, 0);
      }
    }
  }
#pragma unroll
  for (int m = 0; m < NMTW; ++m)
#pragma unroll
    for (int j = 0; j < NOTW; ++j) {
      const int o = ((og * NOTW + j) << 4) + qb;
      const float bv = bias[o];
#pragma unroll
      for (int r = 0; r < 4; ++r) {
        const int qq = ((mt0 + m) << 4) + (kg << 2) + r;
        if (qq < MCAP)
          *(unsigned short*)(bo + (((qq << 8) + (o << 1)) ^ swz(qq))) =
              f2bf(fmaxf(acc[m][j][r] + bv, 0.f));
      }
    }
}

// ---------------------------------------------------------------------------
// k_all: the whole network, cooperative. Grid 256 (qt = bx&3, b = bx>>2).
// LDS arena 87,808 B (reused per phase; block-synced between uses).
// ---------------------------------------------------------------------------
__global__ __launch_bounds__(512, 1)
void k_all(const int* __restrict__ tokens, const float* __restrict__ emb,
           const float* __restrict__ v0, const float* __restrict__ g0,
           const float* __restrict__ vr, const float* __restrict__ gr,
           const float* __restrict__ b0, const float* __restrict__ br,
           const float* __restrict__ de,
           const float* __restrict__ w1, const float* __restrict__ b1,
           const float* __restrict__ w2, const float* __restrict__ b2,
           const float* __restrict__ w3, const float* __restrict__ b3,
           unsigned short* __restrict__ WB0, unsigned short* __restrict__ WBr,
           unsigned short* __restrict__ A0, unsigned short* __restrict__ L2out,
           float* __restrict__ out) {
  __shared__ char lds[87808];
  cg::grid_group grid = cg::this_grid();
  const int tid = threadIdx.x;
  const int bx = blockIdx.x;
  const int qt = bx & 3, b = bx >> 2;
  const int lane = tid & 63, w = tid >> 6;
  const int qb = lane & 15, kg = lane >> 4;

  // ================= Phase W: weight-norm + B pre-swizzle =================
  // WB[((ot*NKS+ks)*64+lane)*8+i], lane=(o&15)|(kg<<4), kk=ks*32+kg*8+i,
  // kk = tap*CPAD + c (CPAD0=320, c>=300 -> 0).
  {
    const int gw = (bx << 3) + w;              // 0..2047; work for <896
    if (gw < 128) {                            // layer 0: K=1500 -> pad 1600
      const int o = gw;
      const float* v = v0 + o * 1500;
      float ss = 0.f;
      for (int i = lane; i < 1500; i += 64) { const float x = v[i]; ss += x * x; }
#pragma unroll
      for (int off = 32; off; off >>= 1) ss += __shfl_xor(ss, off, 64);
      const float scale = g0[o] * rsqrtf(ss);
      const int ot = o >> 4;
      for (int kk = lane; kk < 1600; kk += 64) {
        const int tap = kk / 320, c = kk % 320;
        const float wv = (c < 300) ? v[c * 5 + tap] * scale : 0.f;
        const int ks = kk >> 5;
        const int li = (o & 15) | (((kk >> 3) & 3) << 4);
        WB0[(((ot * 50 + ks) * 64 + li) << 3) | (kk & 7)] = f2bf(wv);
      }
    } else if (gw < 896) {                     // layers 1..6: K=640
      const int idx = gw - 128;
      const int l = idx >> 7, o = idx & 127;
      const float* v = vr + (size_t)(l * 128 + o) * 640;
      float ss = 0.f;
#pragma unroll
      for (int i = 0; i < 10; ++i) { const float x = v[lane + (i << 6)]; ss += x * x; }
#pragma unroll
      for (int off = 32; off; off >>= 1) ss += __shfl_xor(ss, off, 64);
      const float scale = gr[l * 128 + o] * rsqrtf(ss);
      unsigned short* WB = WBr + (size_t)l * 81920;
      const int ot = o >> 4;
#pragma unroll
      for (int i = 0; i < 10; ++i) {
        const int kk = lane + (i << 6);
        const int tap = kk >> 7, c = kk & 127;
        const float wv = v[c * 5 + tap] * scale;
        const int ks = kk >> 5;
        const int li = (o & 15) | (((kk >> 3) & 3) << 4);
        WB[(((ot * 20 + ks) * 64 + li) << 3) | (kk & 7)] = f2bf(wv);
      }
    }
  }
  grid.sync();

  // ================= Phase 0: gather + L0 -> A0 (64 rows/block) ===========
  // embBuf: 133 rows x 656B (p = 128qt + r; p>=509 zeroed; full 640B rows so
  // no undefined bytes reach MFMA). Wave w = ot, 4 m-tiles; A rows <=130.
  // A0 rows b*256 + 64qt + [0..63]; rows >=253 finite garbage (masked later).
  {
    char* embBuf = lds;                        // 87,248 B
    int* toks = (int*)(lds + 87248);           // 134 ints
    if (tid < 134) {
      const int p = (qt << 7) + tid;
      toks[tid] = (tid < 133 && p < 509) ? tokens[(b << 11) + 1539 + p] : -1;
    }
    __syncthreads();
    for (int idx = tid; idx < 133 * 80; idx += 512) {
      const int r = idx / 80, s = idx - r * 80;
      short4v o = {0, 0, 0, 0};
      const int tok = toks[r];
      if (tok >= 0 && s < 75) {
        const float4v v = *(const float4v*)(emb + (size_t)tok * 300 + (s << 2));
        o[0] = (short)f2bf(v[0]); o[1] = (short)f2bf(v[1]);
        o[2] = (short)f2bf(v[2]); o[3] = (short)f2bf(v[3]);
      }
      *(short4v*)(embBuf + r * 656 + (s << 3)) = o;
    }
    __syncthreads();
    floatx4 acc[4];
#pragma unroll
    for (int m = 0; m < 4; ++m) acc[m] = floatx4{0.f, 0.f, 0.f, 0.f};
    const unsigned short* wb0 = WB0 + (size_t)(((w * 50) << 6) + lane) * 8;
#pragma unroll
    for (int tap = 0; tap < 5; ++tap) {
      bfrag8 bf[10];
#pragma unroll
      for (int cs = 0; cs < 10; ++cs)
        bf[cs] = *(const bfrag8*)(wb0 + ((tap * 10 + cs) << 9));
#pragma unroll
      for (int cs = 0; cs < 10; ++cs) {
        const int cb = (cs << 6) + (kg << 4);
#pragma unroll
        for (int m = 0; m < 4; ++m) {
          const int row = (((m << 4) + qb) << 1) + tap;    // <= 130 <= 132
          const bfrag8 a = *(const bfrag8*)(embBuf + row * 656 + cb);
          acc[m] = __builtin_amdgcn_mfma_f32_16x16x32_bf16(a, bf[cs], acc[m], 0, 0, 0);
        }
      }
    }
    unsigned short* ob = A0 + (((size_t)b << 8) + (qt << 6)) * 128;
    const int o = (w << 4) + qb;
    const float bv = b0[o];
#pragma unroll
    for (int m = 0; m < 4; ++m)
#pragma unroll
      for (int r = 0; r < 4; ++r) {
        const int ql = (m << 4) + (kg << 2) + r;           // 0..63
        ob[ql * 128 + o] = f2bf(fmaxf(acc[m][r] + bv, 0.f));
      }
  }
  grid.sync();

  // ================= Phase 1: L1 + L2 -> L2out ============================
  // Stage A0 rows [64qt..64qt+72] (clamp <=255; clamped/garbage rows feed
  // only masked outputs - audited r12). a0stage rows 73..99 zeroed.
  {
    char* a0stage = lds;                       // 100 x 256 = 25,600
    char* l1buf = lds + 25600;                 // 36 x 256 = 9,216
    const char* a0b = (const char*)(A0 + ((size_t)b << 15));
    for (int idx = tid; idx < 100 * 16; idx += 512) {
      const int r = idx >> 4, s = idx & 15;
      float4v v = {0.f, 0.f, 0.f, 0.f};
      if (r < 73) {
        int rs = (qt << 6) + r; if (rs > 255) rs = 255;
        v = *(const float4v*)(a0b + (rs << 8) + (s << 4));
      }
      *(float4v*)(a0stage + (((r << 8) + (s << 4)) ^ swz(r))) = v;
    }
    __syncthreads();
    const int og = w & 3, mgh = w >> 2;
    if (mgh == 0) conv_l<2, 2, 36>(a0stage, l1buf, WBr, br, 0, og, qb, kg, lane);
    else          conv_l<1, 2, 36>(a0stage, l1buf, WBr, br, 2, og, qb, kg, lane);
    __syncthreads();
    // L2: all 8 waves (ot = w); valid l1 rows <=34 read staged A0 <=72.
    floatx4 acc = {0.f, 0.f, 0.f, 0.f};
    const unsigned short* wbl = WBr + 81920;
#pragma unroll
    for (int tap = 0; tap < 5; ++tap) {
      bfrag8 bfs[4];
#pragma unroll
      for (int cs = 0; cs < 4; ++cs)
        bfs[cs] = *(const bfrag8*)(wbl +
            (size_t)(((w * 20 + (tap << 2) + cs) << 6) + lane) * 8);
#pragma unroll
      for (int cs = 0; cs < 4; ++cs) {
        const int cb = (cs << 6) + (kg << 4);
        const int row = (qb << 1) + tap;                   // <= 34 < 36
        const bfrag8 a = *(const bfrag8*)(l1buf + (((row << 8) + cb) ^ swz(row)));
        acc = __builtin_amdgcn_mfma_f32_16x16x32_bf16(a, bfs[cs], acc, 0, 0, 0);
      }
    }
    const int o = (w << 4) + qb;
    const float bv = br[128 + o];
    unsigned short* ob = L2out + ((size_t)b << 13);        // 64 rows x 128
#pragma unroll
    for (int r = 0; r < 4; ++r) {
      const int q2 = (qt << 4) + (kg << 2) + r;
      if (q2 < 61) ob[(q2 << 7) + o] = f2bf(fmaxf(acc[r] + bv, 0.f));
    }
  }
  grid.sync();

  // ================= Phase 2: L3..L6 + head (qt==0 blocks only) ===========
  if (qt == 0) {
    char* bufS = lds;                          // 68 x 256 = 17,408
    char* bufT = lds + 17408;                  // 36 x 256 = 9,216
    float* h1 = (float*)(lds + 26624);
    float* h2 = h1 + 64;
    const char* l2b = (const char*)(L2out + ((size_t)b << 13));
    for (int idx = tid; idx < 61 * 16; idx += 512) {
      const int r = idx >> 4, s = idx & 15;
      *(float4v*)(bufS + (((r << 8) + (s << 4)) ^ swz(r))) =
          *(const float4v*)(l2b + (r << 8) + (s << 4));
    }
    __syncthreads();

    conv_l<1, 2, 32>(bufS, bufT, WBr + 2 * 81920, br + 256, w & 1, w >> 1, qb, kg, lane); // L3 M=29
    __syncthreads();
    conv_l<1, 1, 16>(bufT, bufS, WBr + 3 * 81920, br + 384, 0, w, qb, kg, lane);          // L4 M=13
    __syncthreads();
    conv_l<1, 1, 16>(bufS, bufT, WBr + 4 * 81920, br + 512, 0, w, qb, kg, lane);          // L5 M=5
    __syncthreads();
    conv_l<1, 1, 16>(bufT, bufS, WBr + 5 * 81920, br + 640, 0, w, qb, kg, lane);          // L6 M=1
    __syncthreads();

    // head: combo = [bufS row 0 (swz identity), de] -> 64 -> 32 -> 1
    const unsigned short* o6 = (const unsigned short*)bufS;
    {                                          // h1: 64 outs x 8 threads
      const int o1 = tid >> 3, part = tid & 7;
      const int j0 = part * 18;
      const int j1 = (j0 + 18 < 139) ? j0 + 18 : 139;
      float s = 0.f;
      const float* wrow = w1 + o1 * 139;
      for (int j = j0; j < j1; ++j) {
        const float x = (j < 128) ? bf2f(o6[j]) : de[b * 11 + (j - 128)];
        s += wrow[j] * x;
      }
      s += __shfl_down(s, 4, 64);
      s += __shfl_down(s, 2, 64);
      s += __shfl_down(s, 1, 64);
      if (part == 0) h1[o1] = fmaxf(s + b1[o1], 0.f);
    }
    __syncthreads();
    if (tid < 64) {                            // h2: 32 outs x 2 threads
      const int o2 = tid >> 1, part = tid & 1;
      float s = 0.f;
      const float* wrow = w2 + o2 * 64 + part * 32;
      for (int j = 0; j < 32; ++j) s += wrow[j] * h1[part * 32 + j];
      s += __shfl_down(s, 1, 64);
      if (part == 0) h2[o2] = fmaxf(s + b2[o2], 0.f);
    }
    __syncthreads();
    if (tid < 32) {
      float s = w3[tid] * h2[tid];
      s += __shfl_down(s, 16, 64);
      s += __shfl_down(s, 8, 64);
      s += __shfl_down(s, 4, 64);
      s += __shfl_down(s, 2, 64);
      s += __shfl_down(s, 1, 64);
      if (tid == 0) out[b] = s + b3[0];
    }
  }
}

// ---------------------------------------------------------------------------
extern "C" void kernel_launch(void* const* d_in, const int* in_sizes, int n_in,
                              void* d_out, int out_size, void* d_ws, size_t ws_size,
                              hipStream_t stream) {
  const int*   tokens = (const int*)  d_in[0];
  const float* de     = (const float*)d_in[1];
  const float* emb    = (const float*)d_in[2];
  const float* v0     = (const float*)d_in[3];
  const float* g0     = (const float*)d_in[4];
  const float* b0     = (const float*)d_in[5];
  const float* vr     = (const float*)d_in[6];
  const float* gr     = (const float*)d_in[7];
  const float* br     = (const float*)d_in[8];
  const float* w1     = (const float*)d_in[9];
  const float* b1     = (const float*)d_in[10];
  const float* w2     = (const float*)d_in[11];
  const float* b2     = (const float*)d_in[12];
  const float* w3     = (const float*)d_in[13];
  const float* b3     = (const float*)d_in[14];
  float* outp = (float*)d_out;

  char* ws = (char*)d_ws;
  unsigned short* WB0   = (unsigned short*)(ws + 0);        // 128x1600 bf16
  unsigned short* WBr   = (unsigned short*)(ws + 409600);   // 6 x 128x640 bf16
  unsigned short* A0    = (unsigned short*)(ws + 1392640);  // [64][256][128] bf16
  unsigned short* L2out = (unsigned short*)(ws + 5586944);  // [64][64][128] bf16

  void* args[] = {
    (void*)&tokens, (void*)&emb,
    (void*)&v0, (void*)&g0, (void*)&vr, (void*)&gr,
    (void*)&b0, (void*)&br, (void*)&de,
    (void*)&w1, (void*)&b1, (void*)&w2, (void*)&b2, (void*)&w3, (void*)&b3,
    (void*)&WB0, (void*)&WBr, (void*)&A0, (void*)&L2out, (void*)&outp
  };
  hipLaunchCooperativeKernel((const void*)k_all, dim3(256), dim3(512),
                             args, 0, stream);
}

// Round 14
// 70.939 us; speedup vs baseline: 2.2267x; 2.2267x over previous
//
#include <hip/hip_runtime.h>

// ---------------------------------------------------------------------------
// Devault_Single_CCNN: only the LAST timestep feeds the head -> compute only
// the causal receptive field. Every layer is a stride-2 kernel-5 conv in
// index space: Out[q] = sum_k W[k] In[2q+k], lengths 509->253->125->61->29->
// 13->5->1. bf16 MFMA 16x16x32, fp32 accumulate. THREE dispatches (minimum
// given cross-block deps; r13 showed grid.sync costs ~30us each -> dispatch
// boundaries at ~2.5us are the cheap serialization):
//   k_wnorm  : weight-norm + MFMA-B pre-swizzle (112 blocks x 512).
//   k_conv0g : gather + L0. (8qt x 64b) = 512 blocks (2/CU) x 512 thr, 44KB
//              LDS. ILP gather: thread owns a row-eighth -> 10 independent
//              16B loads. Writes A0 [64][256][128] bf16.
//   k_rest512: L1..L6 + FC head per batch item. 64 blocks x 512 thr, 118KB
//              LDS, bounded per-tap B preloads (<=16 frags, ~150 VGPR, no
//              spill at 512 thr). Replaces r12's conv12+tail3 (saves one
//              boundary + kernel ramp + L2out round-trip).
// Masking invariant: MFMA C-row m depends only on A-row m; garbage/NaN rows
// are confined to masked outputs never read by the valid chain (full audit
// in k_rest512 comments). All LDS overreads stay inside allocations.
// ---------------------------------------------------------------------------

typedef __attribute__((ext_vector_type(8))) short bfrag8;   // 8 bf16
typedef __attribute__((ext_vector_type(4))) float floatx4;  // MFMA acc
typedef __attribute__((ext_vector_type(4))) short short4v;
typedef __attribute__((ext_vector_type(4))) float float4v;

__device__ __forceinline__ unsigned short f2bf(float f) {
  union { float f; unsigned u; } v; v.f = f;
  unsigned r = v.u + 0x7fffu + ((v.u >> 16) & 1u);  // RNE
  return (unsigned short)(r >> 16);
}
__device__ __forceinline__ float bf2f(unsigned short h) {
  union { unsigned u; float f; } v; v.u = ((unsigned)h) << 16;
  return v.f;
}
__device__ __forceinline__ int swz(int row) { return ((row >> 1) & 7) << 4; }

// ---------------------------------------------------------------------------
// k_wnorm: one wave per output channel; butterfly reduce; scatter swizzled WB.
// WB layout: WB[((ot*NKS + ks)*64 + lane)*8 + i], lane=(o&15)|(kg<<4),
//            kk = ks*32 + kg*8 + i, kk = tap*CPAD + c (CPAD0=320, c>=300 -> 0)
// ---------------------------------------------------------------------------
__global__ __launch_bounds__(512)
void k_wnorm(const float* __restrict__ v0, const float* __restrict__ g0,
             const float* __restrict__ vr, const float* __restrict__ gr,
             unsigned short* __restrict__ WB0, unsigned short* __restrict__ WBr) {
  const int gw = (blockIdx.x << 3) + (threadIdx.x >> 6);   // 0..895
  const int lane = threadIdx.x & 63;
  if (gw < 128) {                        // layer 0: K=1500 -> pad 1600
    const int o = gw;
    const float* v = v0 + o * 1500;
    float ss = 0.f;
    for (int i = lane; i < 1500; i += 64) { const float x = v[i]; ss += x * x; }
#pragma unroll
    for (int off = 32; off; off >>= 1) ss += __shfl_xor(ss, off, 64);
    const float scale = g0[o] * rsqrtf(ss);
    const int ot = o >> 4;
    for (int kk = lane; kk < 1600; kk += 64) {
      const int tap = kk / 320, c = kk % 320;
      const float w = (c < 300) ? v[c * 5 + tap] * scale : 0.f;
      const int ks = kk >> 5;
      const int li = (o & 15) | (((kk >> 3) & 3) << 4);
      WB0[(((ot * 50 + ks) * 64 + li) << 3) | (kk & 7)] = f2bf(w);
    }
  } else {                               // layers 1..6: K=640
    const int idx = gw - 128;
    const int l = idx >> 7, o = idx & 127;
    const float* v = vr + (size_t)(l * 128 + o) * 640;
    float ss = 0.f;
#pragma unroll
    for (int i = 0; i < 10; ++i) { const float x = v[lane + (i << 6)]; ss += x * x; }
#pragma unroll
    for (int off = 32; off; off >>= 1) ss += __shfl_xor(ss, off, 64);
    const float scale = gr[l * 128 + o] * rsqrtf(ss);
    unsigned short* WB = WBr + (size_t)l * 81920;
    const int ot = o >> 4;
#pragma unroll
    for (int i = 0; i < 10; ++i) {
      const int kk = lane + (i << 6);
      const int tap = kk >> 7, c = kk & 127;
      const float w = v[c * 5 + tap] * scale;
      const int ks = kk >> 5;
      const int li = (o & 15) | (((kk >> 3) & 3) << 4);
      WB[(((ot * 20 + ks) * 64 + li) << 3) | (kk & 7)] = f2bf(w);
    }
  }
}

// ---------------------------------------------------------------------------
// k_conv0g: gather + L0. Grid (8 qt, 64 b) x 512 thr (8 waves), 2 blocks/CU.
// Block qt: emb rows p = 64qt + [0,66] (p>=509 zeroed) -> embBuf pitch 656B;
// outputs A0 rows 32qt + [0,31]. Wave w: ot = w, 2 m-tiles.
// Gather ILP: thread t owns row (t>>3), eighth e=(t&7): 1 token read -> 10
// independent 16B loads (all in flight) -> 10 converts+stores. Full 640B
// rows staged (no undefined bytes reach MFMA). Per-tap B preload = 10 frags.
// Garbage A0 rows >=253: convolved zeros + bias = finite, masked downstream.
// ---------------------------------------------------------------------------
__global__ __launch_bounds__(512, 4)
void k_conv0g(const int* __restrict__ tokens, const float* __restrict__ emb,
              const unsigned short* __restrict__ WB0, const float* __restrict__ b0,
              unsigned short* __restrict__ A0) {
  __shared__ char embBuf[67 * 656];
  __shared__ int toks[68];
  const int tid = threadIdx.x;
  const int qt = blockIdx.x, b = blockIdx.y;
  if (tid < 68) {
    const int p = (qt << 6) + tid;
    toks[tid] = (tid < 67 && p < 509) ? tokens[(b << 11) + 1539 + p] : -1;
  }
  __syncthreads();
#pragma unroll
  for (int pass = 0; pass < 2; ++pass) {
    const int r = (pass << 6) + (tid >> 3);
    if (r < 67) {
      const int e = tid & 7;
      const int tok = toks[r];
      char* dst = embBuf + r * 656 + e * 80;
      if (tok >= 0) {
        const float* src = emb + (size_t)tok * 300 + e * 40;
#pragma unroll
        for (int k = 0; k < 10; ++k) {
          const int s = e * 10 + k;
          short4v o = {0, 0, 0, 0};
          if (s < 75) {
            const float4v v = *(const float4v*)(src + (k << 2));
            o[0] = (short)f2bf(v[0]); o[1] = (short)f2bf(v[1]);
            o[2] = (short)f2bf(v[2]); o[3] = (short)f2bf(v[3]);
          }
          *(short4v*)(dst + (k << 3)) = o;
        }
      } else {
#pragma unroll
        for (int k = 0; k < 10; ++k)
          *(short4v*)(dst + (k << 3)) = short4v{0, 0, 0, 0};
      }
    }
  }
  __syncthreads();
  const int lane = tid & 63, w = tid >> 6;      // ot = w
  const int qb = lane & 15, kg = lane >> 4;
  floatx4 acc[2];
  acc[0] = floatx4{0.f, 0.f, 0.f, 0.f};
  acc[1] = floatx4{0.f, 0.f, 0.f, 0.f};
  const unsigned short* wb0 = WB0 + (size_t)(((w * 50) << 6) + lane) * 8;
#pragma unroll
  for (int tap = 0; tap < 5; ++tap) {
    bfrag8 bf[10];
#pragma unroll
    for (int cs = 0; cs < 10; ++cs)
      bf[cs] = *(const bfrag8*)(wb0 + ((tap * 10 + cs) << 9));
#pragma unroll
    for (int cs = 0; cs < 10; ++cs) {
      const int cb = (cs << 6) + (kg << 4);
#pragma unroll
      for (int m = 0; m < 2; ++m) {
        const int row = (((m << 4) + qb) << 1) + tap;        // <= 66
        const bfrag8 a = *(const bfrag8*)(embBuf + row * 656 + cb);
        acc[m] = __builtin_amdgcn_mfma_f32_16x16x32_bf16(a, bf[cs], acc[m], 0, 0, 0);
      }
    }
  }
  unsigned short* ob = A0 + (((size_t)b << 8) + (qt << 5)) * 128;
  const int o = (w << 4) + qb;
  const float bv = b0[o];
#pragma unroll
  for (int m = 0; m < 2; ++m)
#pragma unroll
    for (int r = 0; r < 4; ++r) {
      const int ql = (m << 4) + (kg << 2) + r;               // 0..31
      ob[ql * 128 + o] = f2bf(fmaxf(acc[m][r] + bv, 0.f));
    }
}

// ---------------------------------------------------------------------------
// conv_l (proven r12): K=640 layer, NMTW m-tiles at mt0 x NOTW ot's at
// og*NOTW. B per-tap preload (<=16 frags = 64 VGPR). A from swizzled
// 256B-pitch LDS. Stores masked to qq < MCAP (inside destination alloc).
// ---------------------------------------------------------------------------
template<int NMTW, int NOTW, int MCAP>
__device__ __forceinline__ void conv_l(const char* bi, char* bo,
    const unsigned short* __restrict__ WBl, const float* __restrict__ bias,
    int mt0, int og, int qb, int kg, int lane) {
  floatx4 acc[NMTW][NOTW];
#pragma unroll
  for (int m = 0; m < NMTW; ++m)
#pragma unroll
    for (int j = 0; j < NOTW; ++j) acc[m][j] = floatx4{0.f, 0.f, 0.f, 0.f};
#pragma unroll
  for (int tap = 0; tap < 5; ++tap) {
    bfrag8 bfs[NOTW][4];
#pragma unroll
    for (int j = 0; j < NOTW; ++j)
#pragma unroll
      for (int cs = 0; cs < 4; ++cs)
        bfs[j][cs] = *(const bfrag8*)(WBl +
            (size_t)((((og * NOTW + j) * 20 + (tap << 2) + cs) << 6) + lane) * 8);
#pragma unroll
    for (int cs = 0; cs < 4; ++cs) {
      const int cb = (cs << 6) + (kg << 4);
#pragma unroll
      for (int m = 0; m < NMTW; ++m) {
        const int row = (((mt0 + m) << 4) + qb) * 2 + tap;
        const bfrag8 a = *(const bfrag8*)(bi + (((row << 8) + cb) ^ swz(row)));
#pragma unroll
        for (int j = 0; j < NOTW; ++j)
          acc[m][j] = __builtin_amdgcn_mfma_f32_16x16x32_bf16(a, bfs[j][cs], acc[m][j], 0, 0, 0);
      }
    }
  }
#pragma unroll
  for (int m = 0; m < NMTW; ++m)
#pragma unroll
    for (int j = 0; j < NOTW; ++j) {
      const int o = ((og * NOTW + j) << 4) + qb;
      const float bv = bias[o];
#pragma unroll
      for (int r = 0; r < 4; ++r) {
        const int qq = ((mt0 + m) << 4) + (kg << 2) + r;
        if (qq < MCAP)
          *(unsigned short*)(bo + (((qq << 8) + (o << 1)) ^ swz(qq))) =
              f2bf(fmaxf(acc[m][j][r] + bv, 0.f));
      }
    }
}

// ---------------------------------------------------------------------------
// k_rest512: L1..L6 + head, one block per batch. 64 blocks x 512 thr.
// LDS: bufIn 260 rows (staged 253; 253..259 undefined), actP 131, actQ 68.
// Garbage audit (valid chain never reads garbage):
//   L1 valid q<=124 reads bufIn rows <=252 (all staged valid).
//   L1 rows 125..127 may be NaN (read undefined bufIn 253..258) -> stored in
//   actP; L2 valid q<=60 reads actP rows <=124 (valid). L2 garbage rows
//   61..63 (read actP <=130: rows 128..130 undefined-LDS) -> actQ; L3 valid
//   q<=28 reads actQ <=60. L3 masked lanes read actQ rows 64..66 (undefined)
//   -> masked C-rows only (MFMA row isolation). L4 reads actP <=34 (rows
//   32..34 stale L1 out, finite). L5 reads actQ <=34 (16..34 stale L2,
//   finite). L6 reads actP <=34 (stale L3/L1, finite). Head reads actQ row 0
//   = L6 row 0 (valid). All reads inside allocations.
// Wave splits: L1 mt0=(w&3)*2 NMTW=2, og=w>>2 NOTW=4 (8mt x 8ot covered).
// ---------------------------------------------------------------------------
__global__ __launch_bounds__(512, 1)
void k_rest512(const unsigned short* __restrict__ A0, const unsigned short* __restrict__ WBr,
               const float* __restrict__ br, const float* __restrict__ de,
               const float* __restrict__ w1, const float* __restrict__ b1,
               const float* __restrict__ w2, const float* __restrict__ b2,
               const float* __restrict__ w3, const float* __restrict__ b3,
               float* __restrict__ out) {
  __shared__ char lds[66560 + 33536 + 17408 + 384];
  char* bufIn = lds;                     // 260 rows x 256B
  char* actP  = lds + 66560;             // 131 rows
  char* actQ  = lds + 100096;            // 68 rows
  float* h1 = (float*)(lds + 117504);
  float* h2 = h1 + 64;
  const int tid = threadIdx.x, b = blockIdx.x;
  const int lane = tid & 63, w = tid >> 6;
  const int qb = lane & 15, kg = lane >> 4;

  // stage A0 rows 0..252 (coalesced) -> swizzled LDS
  const char* a0b = (const char*)(A0 + ((size_t)b << 15));
  for (int idx = tid; idx < 253 * 16; idx += 512) {
    const int r = idx >> 4, s = idx & 15;
    *(float4v*)(bufIn + (((r << 8) + (s << 4)) ^ swz(r))) =
        *(const float4v*)(a0b + (r << 8) + (s << 4));
  }
  __syncthreads();

  conv_l<2, 4, 128>(bufIn, actP, WBr + 0 * 81920, br + 0,   (w & 3) * 2, w >> 2, qb, kg, lane); // L1 M=125
  __syncthreads();
  conv_l<1, 4, 64>(actP, actQ, WBr + 1 * 81920, br + 128, w & 3, w >> 2, qb, kg, lane);         // L2 M=61
  __syncthreads();
  conv_l<1, 2, 32>(actQ, actP, WBr + 2 * 81920, br + 256, w & 1, w >> 1, qb, kg, lane);         // L3 M=29
  __syncthreads();
  conv_l<1, 1, 16>(actP, actQ, WBr + 3 * 81920, br + 384, 0, w, qb, kg, lane);                  // L4 M=13
  __syncthreads();
  conv_l<1, 1, 16>(actQ, actP, WBr + 4 * 81920, br + 512, 0, w, qb, kg, lane);                  // L5 M=5
  __syncthreads();
  conv_l<1, 1, 16>(actP, actQ, WBr + 5 * 81920, br + 640, 0, w, qb, kg, lane);                  // L6 M=1
  __syncthreads();

  // head: combo = [actQ row 0 (swz identity), de] -> 64 -> 32 -> 1
  const unsigned short* o6 = (const unsigned short*)actQ;
  {                                      // h1: 64 outs x 8 threads
    const int o1 = tid >> 3, part = tid & 7;
    const int j0 = part * 18;
    const int j1 = (j0 + 18 < 139) ? j0 + 18 : 139;
    float s = 0.f;
    const float* wrow = w1 + o1 * 139;
    for (int j = j0; j < j1; ++j) {
      const float x = (j < 128) ? bf2f(o6[j]) : de[b * 11 + (j - 128)];
      s += wrow[j] * x;
    }
    s += __shfl_down(s, 4, 64);
    s += __shfl_down(s, 2, 64);
    s += __shfl_down(s, 1, 64);
    if (part == 0) h1[o1] = fmaxf(s + b1[o1], 0.f);
  }
  __syncthreads();
  if (tid < 64) {                        // h2: 32 outs x 2 threads
    const int o2 = tid >> 1, part = tid & 1;
    float s = 0.f;
    const float* wrow = w2 + o2 * 64 + part * 32;
    for (int j = 0; j < 32; ++j) s += wrow[j] * h1[part * 32 + j];
    s += __shfl_down(s, 1, 64);
    if (part == 0) h2[o2] = fmaxf(s + b2[o2], 0.f);
  }
  __syncthreads();
  if (tid < 32) {
    float s = w3[tid] * h2[tid];
    s += __shfl_down(s, 16, 64);
    s += __shfl_down(s, 8, 64);
    s += __shfl_down(s, 4, 64);
    s += __shfl_down(s, 2, 64);
    s += __shfl_down(s, 1, 64);
    if (tid == 0) out[b] = s + b3[0];
  }
}

// ---------------------------------------------------------------------------
extern "C" void kernel_launch(void* const* d_in, const int* in_sizes, int n_in,
                              void* d_out, int out_size, void* d_ws, size_t ws_size,
                              hipStream_t stream) {
  const int*   tokens = (const int*)  d_in[0];
  const float* de     = (const float*)d_in[1];
  const float* emb    = (const float*)d_in[2];
  const float* v0     = (const float*)d_in[3];
  const float* g0     = (const float*)d_in[4];
  const float* b0     = (const float*)d_in[5];
  const float* vr     = (const float*)d_in[6];
  const float* gr     = (const float*)d_in[7];
  const float* br     = (const float*)d_in[8];
  const float* w1     = (const float*)d_in[9];
  const float* b1     = (const float*)d_in[10];
  const float* w2     = (const float*)d_in[11];
  const float* b2     = (const float*)d_in[12];
  const float* w3     = (const float*)d_in[13];
  const float* b3     = (const float*)d_in[14];
  float* out = (float*)d_out;

  char* w = (char*)d_ws;
  unsigned short* WB0 = (unsigned short*)(w + 0);          // 128x1600 bf16
  unsigned short* WBr = (unsigned short*)(w + 409600);     // 6 x 128x640 bf16
  unsigned short* A0  = (unsigned short*)(w + 1392640);    // [64][256][128] bf16

  hipLaunchKernelGGL(k_wnorm, dim3(112), dim3(512), 0, stream, v0, g0, vr, gr, WB0, WBr);
  hipLaunchKernelGGL(k_conv0g, dim3(8, 64), dim3(512), 0, stream,
                     tokens, emb, WB0, b0, A0);
  hipLaunchKernelGGL(k_rest512, dim3(64), dim3(512), 0, stream,
                     A0, WBr, br, de, w1, b1, w2, b2, w3, b3, out);
}